// Round 4
// baseline (202.194 us; speedup 1.0000x reference)
//
#include <hip/hip_runtime.h>
#include <hip/hip_bf16.h>

typedef short bf16x8 __attribute__((ext_vector_type(8)));
typedef float f32x4 __attribute__((ext_vector_type(4)));
typedef float f32x16 __attribute__((ext_vector_type(16)));
typedef unsigned int uint2v __attribute__((ext_vector_type(2)));

__device__ __forceinline__ float bf2f(ushort u) {
    union { unsigned int i; float f; } v; v.i = ((unsigned int)u) << 16; return v.f;
}
__device__ __forceinline__ ushort f2bf(float f) {
    union { float f; unsigned int i; } v; v.f = f;
    unsigned int x = v.i;
    x += 0x7fffu + ((x >> 16) & 1u);  // RNE (finite values only)
    return (ushort)(x >> 16);
}

#define MFMA(a, b, c) __builtin_amdgcn_mfma_f32_16x16x32_bf16(a, b, c, 0, 0, 0)
#define MFMA32(a, b, c) __builtin_amdgcn_mfma_f32_32x32x16_bf16(a, b, c, 0, 0, 0)

// fine-grained barrier: wait for all but the newest N vmem ops, then s_barrier.
#define WAIT_BARRIER(N) asm volatile("s_waitcnt vmcnt(" #N ")\n\ts_barrier" ::: "memory")

// async global->LDS, 16B/lane; LDS dest = wave-uniform base + lane*16
__device__ __forceinline__ void gld_lds16(const ushort* g, ushort* l) {
    __builtin_amdgcn_global_load_lds(
        (const __attribute__((address_space(1))) unsigned int*)g,
        (__attribute__((address_space(3))) unsigned int*)l, 16, 0, 0);
}

// ws layout (ushort elems)
#define WS_XT 0
#define WS_XS 4194304
#define WS_WQ 8388608
#define WS_WK 9437184
#define WS_WV 10485760
#define WS_WO 11534336
#define WS_QH 12582912
#define WS_KH 16777216
#define WS_VT 20971520
#define WS_AO 0   // reuses XT region (XT dead after qkv_gemm)

// ---------------- cast: fp32 -> bf16 into ws ----------------
__global__ __launch_bounds__(256) void cast_bf16(
    const float* __restrict__ s0, const float* __restrict__ s1,
    const float* __restrict__ s2, const float* __restrict__ s3,
    const float* __restrict__ s4, const float* __restrict__ s5,
    ushort* __restrict__ ws)
{
    const int seg = blockIdx.y;
    const float* src = seg == 0 ? s0 : seg == 1 ? s1 : seg == 2 ? s2
                     : seg == 3 ? s3 : seg == 4 ? s4 : s5;
    const size_t off = seg == 0 ? WS_XT : seg == 1 ? WS_XS : seg == 2 ? WS_WQ
                     : seg == 3 ? WS_WK : seg == 4 ? WS_WV : (size_t)WS_WO;
    const int n4 = (seg < 2) ? 1048576 : 262144;  // float4 count
    ushort* d = ws + off;
    for (int i = blockIdx.x * 256 + threadIdx.x; i < n4; i += gridDim.x * 256) {
        float4 f = ((const float4*)src)[i];
        ushort4 u;
        u.x = f2bf(f.x); u.y = f2bf(f.y); u.z = f2bf(f.z); u.w = f2bf(f.w);
        ((ushort4*)d)[i] = u;
    }
}

// ---------------- qkv GEMM: 128x128 tile, tri-buffer fine-vmcnt --------------
// grid (8, 32, 3): z = 0:Q, 1:K, 2:Vt. All epilogues route through LDS
// for 16B coalesced stores.
__global__ __launch_bounds__(256) void gemm128(
    const ushort* __restrict__ xtb, const ushort* __restrict__ xsb,
    const ushort* __restrict__ wqb, const ushort* __restrict__ wkb,
    const ushort* __restrict__ wvb,
    ushort* __restrict__ qh, ushort* __restrict__ kh, ushort* __restrict__ vt)
{
    __shared__ __align__(16) ushort SM[24576];  // A: 3x4096, B: 12288 + 3x4096

    const int mode = blockIdx.z;
    const ushort* Ap = (mode == 0) ? xtb : xsb;
    const ushort* Wp = (mode == 0) ? wqb : (mode == 1 ? wkb : wvb);

    const int tid  = threadIdx.x;
    const int wave = tid >> 6, lane = tid & 63;
    const int quad = lane >> 4, lidx = lane & 15;
    const int wm = wave >> 1, wn = wave & 1;
    const int m0 = blockIdx.y * 128, n0 = blockIdx.x * 128;

    const int slr = lane >> 2, scb = lane & 3;
    auto stage = [&](int k0, int bufi) {
        ushort* Asb = SM + bufi * 4096;
        ushort* Bsb = SM + 12288 + bufi * 4096;
#pragma unroll
        for (int i2 = 0; i2 < 2; ++i2) {
            const int i = wave + i2 * 4;
            const int r = i * 16 + slr;
            gld_lds16(Ap + (size_t)(m0 + r) * 1024 + k0 + scb * 8, Asb + i * 512);
            gld_lds16(Wp + (size_t)(n0 + r) * 1024 + k0 + scb * 8, Bsb + i * 512);
        }
    };

    f32x4 acc[4][4] = {};
    stage(0, 0);
    stage(32, 1);

    for (int kt = 0; kt < 32; ++kt) {
        const int cur = kt % 3;
        WAIT_BARRIER(4);
        stage(((kt + 2) & 31) * 32, (kt + 2) % 3);
        const ushort* Asb = SM + cur * 4096;
        const ushort* Bsb = SM + 12288 + cur * 4096;
        bf16x8 af[4], bfr[4];
#pragma unroll
        for (int i = 0; i < 4; ++i) {
            af[i]  = *(const bf16x8*)(Asb + (wm * 64 + i * 16 + lidx) * 32 + quad * 8);
            bfr[i] = *(const bf16x8*)(Bsb + (wn * 64 + i * 16 + lidx) * 32 + quad * 8);
        }
#pragma unroll
        for (int mi = 0; mi < 4; ++mi)
#pragma unroll
            for (int ni = 0; ni < 4; ++ni)
                acc[mi][ni] = MFMA(af[mi], bfr[ni], acc[mi][ni]);
    }
    __syncthreads();  // full drain once: epilogue reuses SM as scratch

    ushort* scr = SM + wave * 4096;  // wave-private 8 KB (64x64 tile)

    if (mode == 2) {
        // Vt: scr[dl][swz(tl)] then coalesced stores along t
#pragma unroll
        for (int mi = 0; mi < 4; ++mi)
#pragma unroll
            for (int ni = 0; ni < 4; ++ni)
#pragma unroll
                for (int r = 0; r < 4; ++r) {
                    const int dl = ni * 16 + lidx;
                    const int tl = mi * 16 + quad * 4 + r;
                    const int col = (((tl >> 3) ^ (dl & 7)) << 3) | (tl & 7);
                    scr[dl * 64 + col] = f2bf(acc[mi][ni][r]);
                }
        asm volatile("s_waitcnt lgkmcnt(0)" ::: "memory");
        const int hh = (n0 + wn * 64) >> 6;
        const int bb = m0 >> 11;
        const int t0 = (m0 + wm * 64) & 2047;
        ushort* Vtp = vt + (size_t)(bb * 16 + hh) * 64 * 2048;
#pragma unroll
        for (int ii = 0; ii < 8; ++ii) {
            const int dl = ii * 8 + (lane >> 3);
            const int tb = lane & 7;
            uint4 vd = *(const uint4*)(scr + dl * 64 + ((tb ^ (dl & 7)) << 3));
            *(uint4*)(Vtp + (size_t)dl * 2048 + t0 + tb * 8) = vd;
        }
        return;
    }

    // Q/K: scr[tl][swz(dl)] then coalesced 16B stores along d (one head/wave)
#pragma unroll
    for (int mi = 0; mi < 4; ++mi)
#pragma unroll
        for (int ni = 0; ni < 4; ++ni)
#pragma unroll
            for (int r = 0; r < 4; ++r) {
                const int tl = mi * 16 + quad * 4 + r;
                const int dl = ni * 16 + lidx;
                const int col = (((dl >> 3) ^ (tl & 7)) << 3) | (dl & 7);
                scr[tl * 64 + col] = f2bf(acc[mi][ni][r]);
            }
    asm volatile("s_waitcnt lgkmcnt(0)" ::: "memory");
    {
        ushort* dst = (mode == 0) ? qh : kh;
        const int hh = (n0 + wn * 64) >> 6;
        const int bb = m0 >> 11;
        const int tbase = (m0 + wm * 64) & 2047;
        ushort* Hp = dst + (size_t)(bb * 16 + hh) * 2048 * 64;
#pragma unroll
        for (int ii = 0; ii < 8; ++ii) {
            const int tl = ii * 8 + (lane >> 3);
            const int c  = lane & 7;
            uint4 vd = *(const uint4*)(scr + tl * 64 + ((c ^ (tl & 7)) << 3));
            *(uint4*)(Hp + (size_t)(tbase + tl) * 64 + c * 8) = vd;
        }
    }
}

// ---------------- out GEMM: 128x64 tile, tri-buffer fine-vmcnt ---------------
__global__ __launch_bounds__(256) void gemm_out(
    const ushort* __restrict__ aob, const ushort* __restrict__ wob,
    const float* __restrict__ bias, float* __restrict__ outf)
{
    __shared__ __align__(16) ushort SM[18432];

    const int tid  = threadIdx.x;
    const int wave = tid >> 6, lane = tid & 63;
    const int quad = lane >> 4, lidx = lane & 15;
    const int m0 = blockIdx.y * 128, n0 = blockIdx.x * 64;

    const int slr = lane >> 2, scb = lane & 3;
    auto stage = [&](int k0, int bufi) {
        ushort* Asb = SM + bufi * 4096;
        ushort* Bsb = SM + 12288 + bufi * 2048;
#pragma unroll
        for (int i2 = 0; i2 < 2; ++i2) {
            const int i = wave * 2 + i2;
            gld_lds16(aob + (size_t)(m0 + i * 16 + slr) * 1024 + k0 + scb * 8,
                      Asb + i * 512);
        }
        gld_lds16(wob + (size_t)(n0 + wave * 16 + slr) * 1024 + k0 + scb * 8,
                  Bsb + wave * 512);
    };

    f32x4 acc[2][4] = {};
    stage(0, 0);
    stage(32, 1);

    for (int kt = 0; kt < 32; ++kt) {
        const int cur = kt % 3;
        WAIT_BARRIER(3);
        stage(((kt + 2) & 31) * 32, (kt + 2) % 3);
        const ushort* Asb = SM + cur * 4096;
        const ushort* Bsb = SM + 12288 + cur * 2048;
        bf16x8 af[2], bfr[4];
#pragma unroll
        for (int i = 0; i < 2; ++i)
            af[i] = *(const bf16x8*)(Asb + (wave * 32 + i * 16 + lidx) * 32 + quad * 8);
#pragma unroll
        for (int i = 0; i < 4; ++i)
            bfr[i] = *(const bf16x8*)(Bsb + (i * 16 + lidx) * 32 + quad * 8);
#pragma unroll
        for (int mi = 0; mi < 2; ++mi)
#pragma unroll
            for (int ni = 0; ni < 4; ++ni)
                acc[mi][ni] = MFMA(af[mi], bfr[ni], acc[mi][ni]);
    }

#pragma unroll
    for (int mi = 0; mi < 2; ++mi)
#pragma unroll
        for (int ni = 0; ni < 4; ++ni)
#pragma unroll
            for (int r = 0; r < 4; ++r) {
                const int m = m0 + wave * 32 + mi * 16 + quad * 4 + r;
                const int n = n0 + ni * 16 + lidx;
                outf[(size_t)m * 1024 + n] = acc[mi][ni][r] + bias[n];
            }
}

// ---------------- flash_attn v8: 32x32x16 MFMA, 32 q-rows/wave --------------
// v7 post-mortem: DS-bound (16 b128 frag reads / 16 q-rows / wave-iter = 192
// cyc; 98K cyc/CU = 41us of 52 measured). 32x32x16 MFMA doubles MAC/operand-
// byte: same 16 b128 reads now cover 32 q-rows. S layout (swapped, A=K):
// lane(l31=lane&31, hf=lane>>5) holds S[q=l31][k=32*kb+8g+4hf+(r&3)], so
// cvt_pk pairs + ONE permlane32_swap per word-pair build the PV A-fragment
// in-register (8 swaps/iter, no LDS P). Occupancy drops to 2 waves/SIMD by
// design -- v5's failure mode, but v5's serial killers (P LDS roundtrip +
// vmcnt(0) drains) are gone; serial chain ~500 cyc << per-CU DS service
// (8 waves x 192 cyc). grid (16, 32), 256 thr (4 waves x 32 rows).
__global__ __launch_bounds__(256) void flash_attn(
    const ushort* __restrict__ Qh, const ushort* __restrict__ Kh,
    const ushort* __restrict__ Vt, ushort* __restrict__ AO)
{
    __shared__ __align__(16) ushort Kb[3][4096];
    __shared__ __align__(16) ushort Vb[3][4096];

    const int tid  = threadIdx.x;
    const int wave = tid >> 6, lane = tid & 63;
    const int l31 = lane & 31, hf = lane >> 5;
    const int bh = blockIdx.y;
    const int b = bh >> 4, h = bh & 15;
    const int qbase = blockIdx.x * 128 + wave * 32;

    const ushort* Qp = Qh + (size_t)bh * 2048 * 64;
    const ushort* Kp = Kh + (size_t)bh * 2048 * 64;
    const ushort* Vp = Vt + (size_t)bh * 64 * 2048;

    // Q as B-operand: q[dblk] = Q[qbase+l31][dblk*16 + hf*8 .. +7] * scale
    bf16x8 q[4];
#pragma unroll
    for (int dblk = 0; dblk < 4; ++dblk) {
        const ushort* qr = Qp + (size_t)(qbase + l31) * 64 + dblk * 16 + hf * 8;
        union { ushort u[8]; uint4 v; } t;
        t.v = *(const uint4*)qr;
#pragma unroll
        for (int i = 0; i < 8; ++i)
            ((short*)&q[dblk])[i] = (short)f2bf(bf2f(t.u[i]) * 0.18033688f);
    }

    // stage 64x64 K tile (row-swizzled) + 64x64 Vt tile (d-swizzled)
    // 256 threads x 16B x 2 issues = 8KB per tile
    auto stage = [&](int s0, int bufi) {
#pragma unroll
        for (int i = 0; i < 2; ++i) {
            const int slot = i * 256 + wave * 64 + lane;
            const int r  = slot >> 3;
            const int bb = slot & 7;
            const int gb = bb ^ (r & 7);
            gld_lds16(Kp + (size_t)(s0 + r) * 64 + gb * 8,
                      &Kb[bufi][i * 2048 + wave * 512]);
            gld_lds16(Vp + (size_t)r * 2048 + s0 + gb * 8,
                      &Vb[bufi][i * 2048 + wave * 512]);
        }
    };

    float lsum = 0.f;
    f32x16 o[2] = {};  // o[db]: O[q=(r&3)+8*(r>>2)+4hf][d=db*32+l31]

    stage(0, 0);
    stage(64, 1);

    for (int j = 0; j < 32; ++j) {
        const int cur = j % 3;
        // tile j landed (newest 4 vmem = tile j+1's stage may be in flight)
        WAIT_BARRIER(4);
        stage(((j + 2) & 31) * 64, (j + 2) % 3);

        // QK^T swapped: s[kb] = S[k=32kb+row][q], A=K-frag, B=Q-frag
        f32x16 s[2] = {};
#pragma unroll
        for (int kb = 0; kb < 2; ++kb) {
            const int row = kb * 32 + l31;
#pragma unroll
            for (int dblk = 0; dblk < 4; ++dblk) {
                bf16x8 kf = *(const bf16x8*)
                    &Kb[cur][row * 64 + (((dblk * 2 + hf) ^ (row & 7)) * 8)];
                s[kb] = MFMA32(kf, q[dblk], s[kb]);
            }
        }

        // hoist V fragment reads: latency hides under the softmax VALU block
        // vf[db][c] = V[k=c*16+hf*8 ..][d=db*32+l31] (B-operand for PV)
        bf16x8 vf[2][4];
#pragma unroll
        for (int db = 0; db < 2; ++db) {
            const int drow = db * 32 + l31;
#pragma unroll
            for (int c = 0; c < 4; ++c)
                vf[db][c] = *(const bf16x8*)
                    &Vb[cur][drow * 64 + (((c * 2 + hf) ^ (drow & 7)) * 8)];
        }

        // softmax numerator: exp2 + pack.
        // s[kb] reg r=4g+m2 holds k = 32kb + 8g + 4hf + m2, so regs 4g..4g+3
        // are k-contiguous: W[kb][g][m] covers k = 32kb+8g+4hf+2m+{0,1}.
        uint W[2][4][2];
#pragma unroll
        for (int kb = 0; kb < 2; ++kb)
#pragma unroll
            for (int g = 0; g < 4; ++g) {
                float p0 = __builtin_amdgcn_exp2f(s[kb][4 * g + 0]);
                float p1 = __builtin_amdgcn_exp2f(s[kb][4 * g + 1]);
                float p2 = __builtin_amdgcn_exp2f(s[kb][4 * g + 2]);
                float p3 = __builtin_amdgcn_exp2f(s[kb][4 * g + 3]);
                lsum += (p0 + p1) + (p2 + p3);
                asm("v_cvt_pk_bf16_f32 %0, %1, %2"
                    : "=v"(W[kb][g][0]) : "v"(p0), "v"(p1));
                asm("v_cvt_pk_bf16_f32 %0, %1, %2"
                    : "=v"(W[kb][g][1]) : "v"(p2), "v"(p3));
            }

        // PV: A-frag(c) needs P[q=l31][k=16c+8hf+j]. permlane32_swap of the
        // (g, g+1) word pair gives each half the other's g-word:
        //   ret0 = lanes<32: own W[g], lanes>=32: W[g+1] from lane-32
        //   ret1 = lanes<32: W[g] from lane+32, lanes>=32: own W[g+1]
        // A(c) words = {ret0_m0, ret0_m1, ret1_m0, ret1_m1}.
#pragma unroll
        for (int c = 0; c < 4; ++c) {
            const int kb = c >> 1, gL = (c & 1) * 2;
            uint2v r0 = __builtin_amdgcn_permlane32_swap(
                W[kb][gL][0], W[kb][gL + 1][0], false, false);
            uint2v r1 = __builtin_amdgcn_permlane32_swap(
                W[kb][gL][1], W[kb][gL + 1][1], false, false);
            union { uint u[4]; bf16x8 v; } A;
            A.u[0] = r0[0]; A.u[1] = r1[0]; A.u[2] = r0[1]; A.u[3] = r1[1];
            o[0] = MFMA32(A.v, vf[0][c], o[0]);
            o[1] = MFMA32(A.v, vf[1][c], o[1]);
        }
        // no end-of-iter barrier: next iter's WAIT_BARRIER provides the sync;
        // tri-buffering guarantees stage(j+2) overwrites a buffer last read
        // at iter j-1 (pre-barrier).
    }

    // full row sum for q=l31 in every lane (both halves hold partials)
    lsum += __shfl_xor(lsum, 32);
    const float rcp = 1.0f / lsum;
    float rs[16];
#pragma unroll
    for (int r = 0; r < 16; ++r)
        rs[r] = __shfl(rcp, (r & 3) + 8 * (r >> 2) + 4 * hf);

#pragma unroll
    for (int db = 0; db < 2; ++db)
#pragma unroll
        for (int r = 0; r < 16; ++r) {
            const int qq = (r & 3) + 8 * (r >> 2) + 4 * hf;
            const int tt = qbase + qq;
            const int d  = db * 32 + l31;
            AO[(size_t)(b * 2048 + tt) * 1024 + h * 64 + d] =
                f2bf(o[db][r] * rs[r]);
        }
}

extern "C" void kernel_launch(void* const* d_in, const int* in_sizes, int n_in,
                              void* d_out, int out_size, void* d_ws, size_t ws_size,
                              hipStream_t stream) {
    const float* xt = (const float*)d_in[0];
    const float* xs = (const float*)d_in[1];
    const float* Wq = (const float*)d_in[2];
    const float* Wk = (const float*)d_in[3];
    const float* Wv = (const float*)d_in[4];
    const float* Wo = (const float*)d_in[5];
    const float* bo = (const float*)d_in[6];
    float* out = (float*)d_out;

    ushort* ws = (ushort*)d_ws;

    cast_bf16<<<dim3(1024, 6, 1), 256, 0, stream>>>(xt, xs, Wq, Wk, Wv, Wo, ws);

    gemm128<<<dim3(8, 32, 3), 256, 0, stream>>>(
        ws + WS_XT, ws + WS_XS, ws + WS_WQ, ws + WS_WK, ws + WS_WV,
        ws + WS_QH, ws + WS_KH, ws + WS_VT);

    flash_attn<<<dim3(16, 32, 1), 256, 0, stream>>>(
        ws + WS_QH, ws + WS_KH, ws + WS_VT, ws + WS_AO);

    gemm_out<<<dim3(16, 32, 1), 256, 0, stream>>>(
        ws + WS_AO, ws + WS_WO, bo, out);
}